// Round 1
// baseline (573.016 us; speedup 1.0000x reference)
//
#include <hip/hip_runtime.h>
#include <hip/hip_bf16.h>

typedef unsigned short ushort_t;
typedef unsigned int uint_t;
typedef __attribute__((ext_vector_type(8))) short bf16x8;
typedef __attribute__((ext_vector_type(4))) float f32x4;

#define NB_T 512
#define NB_H 512
#define NB_B 32
#define NB_M (NB_B * NB_T)     // 16384
#define KDIM 1536
#define MAXL 2048

__device__ __forceinline__ ushort_t f2bf(float f) {
  __hip_bfloat16 h = __float2bfloat16(f);
  return *reinterpret_cast<ushort_t*>(&h);
}
__device__ __forceinline__ float bf2f(ushort_t u) {
  __hip_bfloat16 h;
  *reinterpret_cast<ushort_t*>(&h) = u;
  return __bfloat162float(h);
}
__device__ __forceinline__ uint_t pack2(float a, float b) {
  return (uint_t)f2bf(a) | ((uint_t)f2bf(b) << 16);
}
__device__ __forceinline__ void gload_lds16(const void* g, void* l) {
  __builtin_amdgcn_global_load_lds((const __attribute__((address_space(1))) void*)g,
                                   (__attribute__((address_space(3))) void*)l, 16, 0, 0);
}

// ---------------- weight transpose: w[pk][i][o] f32 -> wt[p][o][kk*512+i] bf16
__global__ __launch_bounds__(256) void k_wt(const float* __restrict__ w, ushort_t* __restrict__ wt) {
  __shared__ float tile[64][65];
  const int pk = blockIdx.y;          // p*3+kk
  const int p = pk / 3, kk = pk % 3;
  const int ot = (blockIdx.x & 7) * 64;
  const int it = (blockIdx.x >> 3) * 64;
  const int tx = threadIdx.x & 63;
  const int ty = threadIdx.x >> 6;
  const float* src = w + (size_t)pk * 512 * 512;
  #pragma unroll
  for (int r = ty; r < 64; r += 4)
    tile[r][tx] = src[(size_t)(it + r) * 512 + ot + tx];   // tile[i_local][o_local]
  __syncthreads();
  #pragma unroll
  for (int r = ty; r < 64; r += 4)
    wt[((size_t)(p * 512 + ot + r)) * KDIM + kk * 512 + it + tx] = f2bf(tile[tx][r]);
}

// ---------------- x f32 -> xb_pad bf16 [B][514][512] with zero pad rows; zero ln_pad pad rows
__global__ __launch_bounds__(256) void k_prep_x(const float* __restrict__ x,
                                                ushort_t* __restrict__ xb_pad,
                                                ushort_t* __restrict__ ln_pad) {
  const int rp = blockIdx.x;               // 0..B*514-1
  const int b = rp / 514, j = rp % 514;
  const int tid = threadIdx.x;             // 256 threads, 2 bf16 each
  uint_t* dstA = (uint_t*)(xb_pad + (size_t)rp * 512);
  if (j == 0 || j == 513) {
    dstA[tid] = 0u;
    ((uint_t*)(ln_pad + (size_t)rp * 512))[tid] = 0u;
  } else {
    const float2 xv = ((const float2*)(x + ((size_t)(b * NB_T + j - 1)) * 512))[tid];
    dstA[tid] = pack2(xv.x, xv.y);
  }
}

// ---------------- bucketize targets (searchsorted side='left' over 255 bins)
__global__ __launch_bounds__(256) void k_bucket(const float* __restrict__ pt, const float* __restrict__ et,
                                                const float* __restrict__ pb, const float* __restrict__ eb,
                                                int* __restrict__ pi, int* __restrict__ ei) {
  const int i = blockIdx.x * 256 + threadIdx.x;
  if (i >= NB_M) return;
  float v = pt[i];
  int lo = 0, hi = 255;
  while (lo < hi) { int mid = (lo + hi) >> 1; if (pb[mid] < v) lo = mid + 1; else hi = mid; }
  pi[i] = lo;
  v = et[i]; lo = 0; hi = 255;
  while (lo < hi) { int mid = (lo + hi) >> 1; if (eb[mid] < v) lo = mid + 1; else hi = mid; }
  ei[i] = lo;
}

// ---------------- per-batch cumsum of masked duration, mel_len + mel_mask outputs
__global__ __launch_bounds__(512) void k_cum(const int* __restrict__ dur, const unsigned char* __restrict__ mask,
                                             int* __restrict__ cum, float* __restrict__ mel_len_out,
                                             float* __restrict__ mel_mask_out) {
  __shared__ int s[512];
  const int b = blockIdx.x, t = threadIdx.x;
  int d = mask[b * NB_T + t] ? 0 : dur[b * NB_T + t];
  s[t] = d;
  __syncthreads();
  for (int off = 1; off < 512; off <<= 1) {
    int v = (t >= off) ? s[t - off] : 0;
    __syncthreads();
    s[t] += v;
    __syncthreads();
  }
  cum[b * NB_T + t] = s[t];
  int ml = s[511]; ml = ml < MAXL ? ml : MAXL;
  if (t == 0) mel_len_out[b] = (float)ml;
  for (int f = t; f < MAXL; f += 512)
    mel_mask_out[b * MAXL + f] = (f >= ml) ? 1.0f : 0.0f;
}

// ---------------- conv-as-GEMM: C[128x128] per block, relu(conv+bias) -> bf16 H
// Apad: [B][514][512] bf16 (zero pad rows), Wt: [512][1536] bf16
__global__ __launch_bounds__(256) void k_gemm(const ushort_t* __restrict__ Apad,
                                              const ushort_t* __restrict__ Wt,
                                              const float* __restrict__ bias,
                                              ushort_t* __restrict__ H) {
  __shared__ short lA[128 * 32];
  __shared__ short lB[128 * 32];
  const int tid = threadIdx.x;
  const int lane = tid & 63, wid = tid >> 6;
  const int mt = blockIdx.x >> 2, nt = blockIdx.x & 3;
  const int m0 = mt * 128, n0 = nt * 128;
  const int b = m0 >> 9, t0 = m0 & 511;
  const long Arow0 = (long)b * 514 + t0 + 1;   // padded row index of tile row 0

  const int subr = lane >> 2;          // row within 16-row chunk
  const int ioff = (lane & 3) * 8;     // element offset within 32-wide k-slice

  f32x4 acc[4][4];
  #pragma unroll
  for (int i = 0; i < 4; ++i)
    #pragma unroll
    for (int j = 0; j < 4; ++j) acc[i][j] = (f32x4)0.f;

  const int wr = wid >> 1, wc = wid & 1;
  const int lr = lane & 15, kg = lane >> 4;

  for (int kk = 0; kk < 48; ++kk) {
    const int dt = (kk >> 4) - 1;          // conv tap: -1, 0, +1
    const int i0 = (kk & 15) << 5;         // input-channel offset
    #pragma unroll
    for (int q = 0; q < 2; ++q) {          // A stage: 8KB total, 4 waves x 2 issues
      const int chunk = wid * 2 + q;
      const int r = chunk * 16 + subr;
      const ushort_t* gsrc = Apad + (size_t)(Arow0 + r + dt) * 512 + i0 + ioff;
      gload_lds16(gsrc, &lA[chunk * 512]);
    }
    #pragma unroll
    for (int q = 0; q < 2; ++q) {          // B stage
      const int chunk = wid * 2 + q;
      const int r = chunk * 16 + subr;
      const ushort_t* gsrc = Wt + (size_t)(n0 + r) * KDIM + kk * 32 + ioff;
      gload_lds16(gsrc, &lB[chunk * 512]);
    }
    __syncthreads();
    bf16x8 af[4], bfv[4];
    #pragma unroll
    for (int fi = 0; fi < 4; ++fi)
      af[fi] = *(const bf16x8*)&lA[(wr * 64 + fi * 16 + lr) * 32 + kg * 8];
    #pragma unroll
    for (int fj = 0; fj < 4; ++fj)
      bfv[fj] = *(const bf16x8*)&lB[(wc * 64 + fj * 16 + lr) * 32 + kg * 8];
    #pragma unroll
    for (int fi = 0; fi < 4; ++fi)
      #pragma unroll
      for (int fj = 0; fj < 4; ++fj)
        acc[fi][fj] = __builtin_amdgcn_mfma_f32_16x16x32_bf16(af[fi], bfv[fj], acc[fi][fj], 0, 0, 0);
    __syncthreads();
  }

  // epilogue: bias + relu -> bf16
  #pragma unroll
  for (int fi = 0; fi < 4; ++fi) {
    const int row = m0 + wr * 64 + fi * 16 + kg * 4;
    #pragma unroll
    for (int fj = 0; fj < 4; ++fj) {
      const int col = n0 + wc * 64 + fj * 16 + lr;
      const float bv = bias[col];
      #pragma unroll
      for (int r = 0; r < 4; ++r) {
        float v = acc[fi][fj][r] + bv;
        v = v > 0.f ? v : 0.f;
        H[(size_t)(row + r) * 512 + col] = f2bf(v);
      }
    }
  }
}

// ---------------- LayerNorm (wave per row) -> padded bf16 buffer for next conv
__global__ __launch_bounds__(256) void k_ln_mid(const ushort_t* __restrict__ Hh,
                                                const float* __restrict__ g, const float* __restrict__ bb,
                                                ushort_t* __restrict__ out_pad) {
  const int row = blockIdx.x * 4 + (threadIdx.x >> 6);
  const int lane = threadIdx.x & 63;
  bf16x8 v = *(const bf16x8*)(Hh + (size_t)row * 512 + lane * 8);
  float xv[8];
  float s = 0.f;
  #pragma unroll
  for (int j = 0; j < 8; ++j) { xv[j] = bf2f((ushort_t)v[j]); s += xv[j]; }
  #pragma unroll
  for (int m = 32; m >= 1; m >>= 1) s += __shfl_xor(s, m, 64);
  const float mean = s * (1.f / 512.f);
  float vs = 0.f;
  #pragma unroll
  for (int j = 0; j < 8; ++j) { float d = xv[j] - mean; vs += d * d; }
  #pragma unroll
  for (int m = 32; m >= 1; m >>= 1) vs += __shfl_xor(vs, m, 64);
  const float rstd = rsqrtf(vs * (1.f / 512.f) + 1e-5f);
  const float4 g0 = ((const float4*)(g + lane * 8))[0];
  const float4 g1 = ((const float4*)(g + lane * 8))[1];
  const float4 b0 = ((const float4*)(bb + lane * 8))[0];
  const float4 b1 = ((const float4*)(bb + lane * 8))[1];
  const float gg[8] = {g0.x, g0.y, g0.z, g0.w, g1.x, g1.y, g1.z, g1.w};
  const float bv[8] = {b0.x, b0.y, b0.z, b0.w, b1.x, b1.y, b1.z, b1.w};
  bf16x8 o;
  #pragma unroll
  for (int j = 0; j < 8; ++j) o[j] = (short)f2bf((xv[j] - mean) * rstd * gg[j] + bv[j]);
  const int bidx = row >> 9, t = row & 511;
  *(bf16x8*)(out_pad + ((size_t)(bidx * 514 + t + 1)) * 512 + lane * 8) = o;
}

// ---------------- LayerNorm + linear projection to scalar + mask -> pred output
__global__ __launch_bounds__(256) void k_ln_fin(const ushort_t* __restrict__ Hh,
                                                const float* __restrict__ g, const float* __restrict__ bb,
                                                const float* __restrict__ lw, const float* __restrict__ lbp,
                                                const unsigned char* __restrict__ mask,
                                                float* __restrict__ outp) {
  const int row = blockIdx.x * 4 + (threadIdx.x >> 6);
  const int lane = threadIdx.x & 63;
  bf16x8 v = *(const bf16x8*)(Hh + (size_t)row * 512 + lane * 8);
  float xv[8];
  float s = 0.f;
  #pragma unroll
  for (int j = 0; j < 8; ++j) { xv[j] = bf2f((ushort_t)v[j]); s += xv[j]; }
  #pragma unroll
  for (int m = 32; m >= 1; m >>= 1) s += __shfl_xor(s, m, 64);
  const float mean = s * (1.f / 512.f);
  float vs = 0.f;
  #pragma unroll
  for (int j = 0; j < 8; ++j) { float d = xv[j] - mean; vs += d * d; }
  #pragma unroll
  for (int m = 32; m >= 1; m >>= 1) vs += __shfl_xor(vs, m, 64);
  const float rstd = rsqrtf(vs * (1.f / 512.f) + 1e-5f);
  const float4 g0 = ((const float4*)(g + lane * 8))[0];
  const float4 g1 = ((const float4*)(g + lane * 8))[1];
  const float4 b0 = ((const float4*)(bb + lane * 8))[0];
  const float4 b1 = ((const float4*)(bb + lane * 8))[1];
  const float4 w0 = ((const float4*)(lw + lane * 8))[0];
  const float4 w1 = ((const float4*)(lw + lane * 8))[1];
  const float gg[8] = {g0.x, g0.y, g0.z, g0.w, g1.x, g1.y, g1.z, g1.w};
  const float bv[8] = {b0.x, b0.y, b0.z, b0.w, b1.x, b1.y, b1.z, b1.w};
  const float ww[8] = {w0.x, w0.y, w0.z, w0.w, w1.x, w1.y, w1.z, w1.w};
  float dot = 0.f;
  #pragma unroll
  for (int j = 0; j < 8; ++j) dot += ((xv[j] - mean) * rstd * gg[j] + bv[j]) * ww[j];
  #pragma unroll
  for (int m = 32; m >= 1; m >>= 1) dot += __shfl_xor(dot, m, 64);
  if (lane == 0) {
    float val = dot + lbp[0];
    if (mask[row]) val = 0.f;
    outp[row] = val;
  }
}

// ---------------- x2 = x + table[idx]; also write bf16 padded copy for next predictor
__global__ __launch_bounds__(256) void k_addemb1(const float* __restrict__ x, const float* __restrict__ tab,
                                                 const int* __restrict__ idx, float* __restrict__ x2f,
                                                 ushort_t* __restrict__ xb_pad) {
  const int m = blockIdx.x, tid = threadIdx.x;
  const int b = m >> 9, t = m & 511;
  const float2 xv = ((const float2*)(x + (size_t)m * 512))[tid];
  const float2 tv = ((const float2*)(tab + (size_t)idx[m] * 512))[tid];
  float2 r; r.x = xv.x + tv.x; r.y = xv.y + tv.y;
  ((float2*)(x2f + (size_t)m * 512))[tid] = r;
  ((uint_t*)(xb_pad + ((size_t)(b * 514 + t + 1)) * 512))[tid] = pack2(r.x, r.y);
}

// ---------------- x2 += table[idx] (f32 in place)
__global__ __launch_bounds__(256) void k_addemb2(const float* __restrict__ tab, const int* __restrict__ idx,
                                                 float* __restrict__ x2f) {
  const int m = blockIdx.x, tid = threadIdx.x;
  const float2 tv = ((const float2*)(tab + (size_t)idx[m] * 512))[tid];
  float2 r = ((const float2*)(x2f + (size_t)m * 512))[tid];
  r.x += tv.x; r.y += tv.y;
  ((float2*)(x2f + (size_t)m * 512))[tid] = r;
}

// ---------------- length regulator: block per (b, frame), 128 threads x float4
__global__ __launch_bounds__(128) void k_regulate(const float* __restrict__ x2f, const int* __restrict__ cum,
                                                  float* __restrict__ xout) {
  const int bid = blockIdx.x;
  const int b = bid >> 11, f = bid & 2047;
  const int* c = cum + b * NB_T;
  int ml = c[511]; ml = ml < MAXL ? ml : MAXL;
  const int tid = threadIdx.x;
  float4 val = make_float4(0.f, 0.f, 0.f, 0.f);
  if (f < ml) {
    int lo = 0, hi = 512;
    while (lo < hi) { int mid = (lo + hi) >> 1; if (c[mid] <= f) lo = mid + 1; else hi = mid; }
    if (lo > 511) lo = 511;
    val = ((const float4*)(x2f + ((size_t)(b * NB_T + lo)) * 512))[tid];
  }
  ((float4*)(xout + ((size_t)(b * MAXL + f)) * 512))[tid] = val;
}

extern "C" void kernel_launch(void* const* d_in, const int* in_sizes, int n_in,
                              void* d_out, int out_size, void* d_ws, size_t ws_size,
                              hipStream_t stream) {
  const float* x        = (const float*)d_in[0];
  const unsigned char* src_mask = (const unsigned char*)d_in[1];
  const int* duration   = (const int*)d_in[2];
  const float* pitch_t  = (const float*)d_in[3];
  const float* energy_t = (const float*)d_in[4];
  const float* conv1_w  = (const float*)d_in[5];
  const float* conv1_b  = (const float*)d_in[6];
  const float* ln1_g    = (const float*)d_in[7];
  const float* ln1_b    = (const float*)d_in[8];
  const float* conv2_w  = (const float*)d_in[9];
  const float* conv2_b  = (const float*)d_in[10];
  const float* ln2_g    = (const float*)d_in[11];
  const float* ln2_b    = (const float*)d_in[12];
  const float* lin_w    = (const float*)d_in[13];
  const float* lin_b    = (const float*)d_in[14];
  const float* pbins    = (const float*)d_in[15];
  const float* ebins    = (const float*)d_in[16];
  const float* ptab     = (const float*)d_in[17];
  const float* etab     = (const float*)d_in[18];

  char* ws = (char*)d_ws;
  ushort_t* xb_pad = (ushort_t*)(ws + 0);            // 16,842,752 B
  ushort_t* ln_pad = (ushort_t*)(ws + 16842752);     // 16,842,752 B
  ushort_t* wt1    = (ushort_t*)(ws + 33685504);     //  4,718,592 B
  ushort_t* wt2    = (ushort_t*)(ws + 38404096);     //  4,718,592 B
  ushort_t* hbuf   = (ushort_t*)(ws + 43122688);     // 16,777,216 B
  float*    x2f    = (float*)   (ws + 59899904);     // 33,554,432 B
  int*      p_idx  = (int*)     (ws + 93454336);
  int*      e_idx  = (int*)     (ws + 93519872);
  int*      cum    = (int*)     (ws + 93585408);

  float* out      = (float*)d_out;
  float* o_xout   = out;                       // 33,554,432
  float* o_logd   = out + 33554432;            // 16384
  float* o_pitch  = o_logd + 16384;
  float* o_energy = o_pitch + 16384;
  float* o_mellen = o_energy + 16384;          // 32
  float* o_mmask  = o_mellen + 32;             // 65536

  // prep
  k_wt<<<dim3(64, 9), 256, 0, stream>>>(conv1_w, wt1);
  k_wt<<<dim3(64, 9), 256, 0, stream>>>(conv2_w, wt2);
  k_prep_x<<<NB_B * 514, 256, 0, stream>>>(x, xb_pad, ln_pad);
  k_bucket<<<NB_M / 256, 256, 0, stream>>>(pitch_t, energy_t, pbins, ebins, p_idx, e_idx);
  k_cum<<<NB_B, 512, 0, stream>>>(duration, src_mask, cum, o_mellen, o_mmask);

  // predictor 0: duration (input x)
  k_gemm<<<512, 256, 0, stream>>>(xb_pad, wt1, conv1_b, hbuf);
  k_ln_mid<<<NB_M / 4, 256, 0, stream>>>(hbuf, ln1_g, ln1_b, ln_pad);
  k_gemm<<<512, 256, 0, stream>>>(ln_pad, wt2, conv2_b, hbuf);
  k_ln_fin<<<NB_M / 4, 256, 0, stream>>>(hbuf, ln2_g, ln2_b, lin_w, lin_b, src_mask, o_logd);

  // predictor 1: pitch (input x)
  k_gemm<<<512, 256, 0, stream>>>(xb_pad, wt1 + (size_t)1 * 512 * KDIM, conv1_b + 512, hbuf);
  k_ln_mid<<<NB_M / 4, 256, 0, stream>>>(hbuf, ln1_g + 512, ln1_b + 512, ln_pad);
  k_gemm<<<512, 256, 0, stream>>>(ln_pad, wt2 + (size_t)1 * 512 * KDIM, conv2_b + 512, hbuf);
  k_ln_fin<<<NB_M / 4, 256, 0, stream>>>(hbuf, ln2_g + 512, ln2_b + 512, lin_w + 512, lin_b + 1, src_mask, o_pitch);

  // x2 = x + pitch_emb  (f32 + bf16 padded overwrite of xb_pad)
  k_addemb1<<<NB_M, 256, 0, stream>>>(x, ptab, p_idx, x2f, xb_pad);

  // predictor 2: energy (input x2)
  k_gemm<<<512, 256, 0, stream>>>(xb_pad, wt1 + (size_t)2 * 512 * KDIM, conv1_b + 1024, hbuf);
  k_ln_mid<<<NB_M / 4, 256, 0, stream>>>(hbuf, ln1_g + 1024, ln1_b + 1024, ln_pad);
  k_gemm<<<512, 256, 0, stream>>>(ln_pad, wt2 + (size_t)2 * 512 * KDIM, conv2_b + 1024, hbuf);
  k_ln_fin<<<NB_M / 4, 256, 0, stream>>>(hbuf, ln2_g + 1024, ln2_b + 1024, lin_w + 1024, lin_b + 2, src_mask, o_energy);

  // x3 = x2 + energy_emb (in place)
  k_addemb2<<<NB_M, 256, 0, stream>>>(etab, e_idx, x2f);

  // length regulator
  k_regulate<<<NB_B * MAXL, 128, 0, stream>>>(x2f, cum, o_xout);
}

// Round 4
// 503.219 us; speedup vs baseline: 1.1387x; 1.1387x over previous
//
#include <hip/hip_runtime.h>
#include <hip/hip_bf16.h>

typedef unsigned short ushort_t;
typedef unsigned int uint_t;
typedef __attribute__((ext_vector_type(8))) short bf16x8;
typedef __attribute__((ext_vector_type(4))) float f32x4;

#define NB_T 512
#define NB_B 32
#define NB_M (NB_B * NB_T)     // 16384
#define KDIM 1536
#define MAXL 2048
#define EPI_STRIDE 144         // shorts; 288 B = 18*16 -> 16B-aligned rows, bank shift 8/row

__device__ __forceinline__ ushort_t f2bf(float f) {
  __hip_bfloat16 h = __float2bfloat16(f);
  return *reinterpret_cast<ushort_t*>(&h);
}
__device__ __forceinline__ float bf2f(ushort_t u) {
  __hip_bfloat16 h;
  *reinterpret_cast<ushort_t*>(&h) = u;
  return __bfloat162float(h);
}
__device__ __forceinline__ uint_t pack2(float a, float b) {
  return (uint_t)f2bf(a) | ((uint_t)f2bf(b) << 16);
}
__device__ __forceinline__ void gload_lds16(const void* g, void* l) {
  __builtin_amdgcn_global_load_lds((const __attribute__((address_space(1))) void*)g,
                                   (__attribute__((address_space(3))) void*)l, 16, 0, 0);
}

// ---------------- weight transpose: w[pk][i][o] f32 -> wt[p][o][kk*512+i] bf16
__global__ __launch_bounds__(256) void k_wt(const float* __restrict__ w, ushort_t* __restrict__ wt) {
  __shared__ float tile[64][65];
  const int pk = blockIdx.y;          // p*3+kk
  const int p = pk / 3, kk = pk % 3;
  const int ot = (blockIdx.x & 7) * 64;
  const int it = (blockIdx.x >> 3) * 64;
  const int tx = threadIdx.x & 63;
  const int ty = threadIdx.x >> 6;
  const float* src = w + (size_t)pk * 512 * 512;
  #pragma unroll
  for (int r = ty; r < 64; r += 4)
    tile[r][tx] = src[(size_t)(it + r) * 512 + ot + tx];
  __syncthreads();
  #pragma unroll
  for (int r = ty; r < 64; r += 4)
    wt[((size_t)(p * 512 + ot + r)) * KDIM + kk * 512 + it + tx] = f2bf(tile[tx][r]);
}

// ---------------- bucketize targets
__global__ __launch_bounds__(256) void k_bucket(const float* __restrict__ pt, const float* __restrict__ et,
                                                const float* __restrict__ pb, const float* __restrict__ eb,
                                                int* __restrict__ pi, int* __restrict__ ei) {
  const int i = blockIdx.x * 256 + threadIdx.x;
  if (i >= NB_M) return;
  float v = pt[i];
  int lo = 0, hi = 255;
  while (lo < hi) { int mid = (lo + hi) >> 1; if (pb[mid] < v) lo = mid + 1; else hi = mid; }
  pi[i] = lo;
  v = et[i]; lo = 0; hi = 255;
  while (lo < hi) { int mid = (lo + hi) >> 1; if (eb[mid] < v) lo = mid + 1; else hi = mid; }
  ei[i] = lo;
}

// ---------------- per-batch cumsum of masked duration, mel_len + mel_mask outputs
__global__ __launch_bounds__(512) void k_cum(const int* __restrict__ dur, const unsigned char* __restrict__ mask,
                                             int* __restrict__ cum, float* __restrict__ mel_len_out,
                                             float* __restrict__ mel_mask_out) {
  __shared__ int s[512];
  const int b = blockIdx.x, t = threadIdx.x;
  int d = mask[b * NB_T + t] ? 0 : dur[b * NB_T + t];
  s[t] = d;
  __syncthreads();
  for (int off = 1; off < 512; off <<= 1) {
    int v = (t >= off) ? s[t - off] : 0;
    __syncthreads();
    s[t] += v;
    __syncthreads();
  }
  cum[b * NB_T + t] = s[t];
  int ml = s[511]; ml = ml < MAXL ? ml : MAXL;
  if (t == 0) mel_len_out[b] = (float)ml;
  for (int f = t; f < MAXL; f += 512)
    mel_mask_out[b * MAXL + f] = (f >= ml) ? 1.0f : 0.0f;
}

// ---------------- fused prep: xb_pad = bf(x), x2pad = bf(x + ptab[pidx]),
//                  x3f = x + ptab + etab (f32), zero pad rows (xb/x2/lnp2)
__global__ __launch_bounds__(256) void k_prep(const float* __restrict__ x,
                                              const float* __restrict__ ptab, const float* __restrict__ etab,
                                              const int* __restrict__ pidx, const int* __restrict__ eidx,
                                              ushort_t* __restrict__ xb_pad, ushort_t* __restrict__ x2pad,
                                              ushort_t* __restrict__ lnp2, float* __restrict__ x3f) {
  const int rp = blockIdx.x;               // 0..B*514-1
  const int b = rp / 514, j = rp % 514;
  const int tid = threadIdx.x;             // 2 elements each
  if (j == 0 || j == 513) {
    ((uint_t*)(xb_pad + (size_t)rp * 512))[tid] = 0u;
    ((uint_t*)(x2pad + (size_t)rp * 512))[tid] = 0u;
    ((uint_t*)(lnp2 + (size_t)rp * 512))[tid] = 0u;
    return;
  }
  const int m = b * NB_T + j - 1;
  const float2 xv = ((const float2*)(x + (size_t)m * 512))[tid];
  const float2 pv = ((const float2*)(ptab + (size_t)pidx[m] * 512))[tid];
  const float2 ev = ((const float2*)(etab + (size_t)eidx[m] * 512))[tid];
  ((uint_t*)(xb_pad + (size_t)rp * 512))[tid] = pack2(xv.x, xv.y);
  const float ax = xv.x + pv.x, ay = xv.y + pv.y;
  ((uint_t*)(x2pad + (size_t)rp * 512))[tid] = pack2(ax, ay);
  float2 o; o.x = ax + ev.x; o.y = ay + ev.y;
  ((float2*)(x3f + (size_t)m * 512))[tid] = o;
}

// ---------------- batched conv-as-GEMM, 3 predictors, 128x128 tile, dbuf LDS, 1 barrier/K-step
__global__ __launch_bounds__(256) void k_gemm(const ushort_t* __restrict__ A0,
                                              const ushort_t* __restrict__ A1,
                                              const ushort_t* __restrict__ A2,
                                              const ushort_t* __restrict__ Wt,
                                              const float* __restrict__ bias,
                                              ushort_t* __restrict__ H) {
  __shared__ short smem[18432];   // loop: 2 bufs x (A 4096 + B 4096) = 32KB; epi: 128x144 = 36KB
  const int tid = threadIdx.x;
  const int lane = tid & 63, wid = tid >> 6;

  // bijective XCD-chunked swizzle: 1536 blocks, q = 192 per XCD
  const int h = blockIdx.x;
  const int logical = (h & 7) * 192 + (h >> 3);
  const int pred = logical >> 9;
  const int tile = logical & 511;
  const int mt = tile >> 2, nt = tile & 3;
  const int m0 = mt * 128, n0 = nt * 128;
  const int b = m0 >> 9, t0 = m0 & 511;
  const long Arow0 = (long)b * 514 + t0 + 1;

  const ushort_t* Ap = (pred == 0) ? A0 : ((pred == 1) ? A1 : A2);
  const ushort_t* Wp = Wt + (size_t)pred * 512 * KDIM;
  const float* bp = bias + pred * 512;
  ushort_t* Hp = H + (size_t)pred * NB_M * 512;

  const int subr = lane >> 2;
  const int ioff = (lane & 3) * 8;
  const int wr = wid >> 1, wc = wid & 1;
  const int lr = lane & 15, kg = lane >> 4;

  f32x4 acc[4][4];
  #pragma unroll
  for (int i = 0; i < 4; ++i)
    #pragma unroll
    for (int j = 0; j < 4; ++j) acc[i][j] = (f32x4)0.f;

  auto STAGE = [&](int kk, int buf) {
    const int dt = (kk >> 4) - 1;
    const int i0 = (kk & 15) << 5;
    short* la = &smem[buf * 8192];
    short* lb = &smem[buf * 8192 + 4096];
    #pragma unroll
    for (int q = 0; q < 2; ++q) {
      const int chunk = wid * 2 + q;
      const int r = chunk * 16 + subr;
      gload_lds16(Ap + (size_t)(Arow0 + r + dt) * 512 + i0 + ioff, &la[chunk * 512]);
      gload_lds16(Wp + (size_t)(n0 + r) * KDIM + kk * 32 + ioff, &lb[chunk * 512]);
    }
  };

  STAGE(0, 0);
  __syncthreads();
  int buf = 0;
  for (int kk = 0; kk < 48; ++kk) {
    if (kk < 47) STAGE(kk + 1, buf ^ 1);
    const short* la = &smem[buf * 8192];
    const short* lb = &smem[buf * 8192 + 4096];
    bf16x8 af[4], bfv[4];
    #pragma unroll
    for (int fi = 0; fi < 4; ++fi)
      af[fi] = *(const bf16x8*)&la[(wr * 64 + fi * 16 + lr) * 32 + kg * 8];
    #pragma unroll
    for (int fj = 0; fj < 4; ++fj)
      bfv[fj] = *(const bf16x8*)&lb[(wc * 64 + fj * 16 + lr) * 32 + kg * 8];
    #pragma unroll
    for (int fi = 0; fi < 4; ++fi)
      #pragma unroll
      for (int fj = 0; fj < 4; ++fj)
        acc[fi][fj] = __builtin_amdgcn_mfma_f32_16x16x32_bf16(af[fi], bfv[fj], acc[fi][fj], 0, 0, 0);
    __syncthreads();   // drains vmcnt (next-tile stage) + covers LDS reuse
    buf ^= 1;
  }

  // epilogue: bias + relu -> bf16 via LDS bounce, then coalesced 16B stores
  float bvv[4];
  #pragma unroll
  for (int fj = 0; fj < 4; ++fj) bvv[fj] = bp[n0 + wc * 64 + fj * 16 + lr];
  #pragma unroll
  for (int fi = 0; fi < 4; ++fi) {
    const int rowb = wr * 64 + fi * 16 + kg * 4;
    #pragma unroll
    for (int fj = 0; fj < 4; ++fj) {
      const int col = wc * 64 + fj * 16 + lr;
      #pragma unroll
      for (int r = 0; r < 4; ++r) {
        float v = acc[fi][fj][r] + bvv[fj];
        v = v > 0.f ? v : 0.f;
        smem[(rowb + r) * EPI_STRIDE + col] = (short)f2bf(v);
      }
    }
  }
  __syncthreads();
  #pragma unroll
  for (int s = 0; s < 8; ++s) {
    const int chunk = tid + s * 256;        // 0..2047
    const int row = chunk >> 4, c8 = (chunk & 15) * 8;
    bf16x8 vv = *(const bf16x8*)&smem[row * EPI_STRIDE + c8];
    *(bf16x8*)(Hp + (size_t)(m0 + row) * 512 + n0 + c8) = vv;
  }
}

// ---------------- batched LayerNorm (wave per row) -> padded bf16 buffers
__global__ __launch_bounds__(256) void k_ln_mid(const ushort_t* __restrict__ Hh,
                                                const float* __restrict__ g, const float* __restrict__ bb,
                                                ushort_t* __restrict__ lnp0, ushort_t* __restrict__ lnp1,
                                                ushort_t* __restrict__ lnp2) {
  const int rr = blockIdx.x * 4 + (threadIdx.x >> 6);   // 0..3*NB_M-1
  const int pred = rr >> 14, m = rr & (NB_M - 1);
  const int lane = threadIdx.x & 63;
  const float* gp = g + pred * 512;
  const float* bp = bb + pred * 512;
  ushort_t* dst = (pred == 0) ? lnp0 : ((pred == 1) ? lnp1 : lnp2);
  bf16x8 v = *(const bf16x8*)(Hh + (size_t)rr * 512 + lane * 8);
  float xv[8];
  float s = 0.f;
  #pragma unroll
  for (int j = 0; j < 8; ++j) { xv[j] = bf2f((ushort_t)v[j]); s += xv[j]; }
  #pragma unroll
  for (int mm = 32; mm >= 1; mm >>= 1) s += __shfl_xor(s, mm, 64);
  const float mean = s * (1.f / 512.f);
  float vs = 0.f;
  #pragma unroll
  for (int j = 0; j < 8; ++j) { float d = xv[j] - mean; vs += d * d; }
  #pragma unroll
  for (int mm = 32; mm >= 1; mm >>= 1) vs += __shfl_xor(vs, mm, 64);
  const float rstd = rsqrtf(vs * (1.f / 512.f) + 1e-5f);
  const float4 g0 = ((const float4*)(gp + lane * 8))[0];
  const float4 g1 = ((const float4*)(gp + lane * 8))[1];
  const float4 b0 = ((const float4*)(bp + lane * 8))[0];
  const float4 b1 = ((const float4*)(bp + lane * 8))[1];
  const float gg[8] = {g0.x, g0.y, g0.z, g0.w, g1.x, g1.y, g1.z, g1.w};
  const float bv[8] = {b0.x, b0.y, b0.z, b0.w, b1.x, b1.y, b1.z, b1.w};
  bf16x8 o;
  #pragma unroll
  for (int j = 0; j < 8; ++j) o[j] = (short)f2bf((xv[j] - mean) * rstd * gg[j] + bv[j]);
  const int bidx = m >> 9, t = m & 511;
  *(bf16x8*)(dst + ((size_t)(bidx * 514 + t + 1)) * 512 + lane * 8) = o;
}

// ---------------- batched LayerNorm + linear proj + mask -> 3 pred outputs (contiguous)
__global__ __launch_bounds__(256) void k_ln_fin(const ushort_t* __restrict__ Hh,
                                                const float* __restrict__ g, const float* __restrict__ bb,
                                                const float* __restrict__ lw, const float* __restrict__ lbp,
                                                const unsigned char* __restrict__ mask,
                                                float* __restrict__ outp) {
  const int rr = blockIdx.x * 4 + (threadIdx.x >> 6);
  const int pred = rr >> 14, m = rr & (NB_M - 1);
  const int lane = threadIdx.x & 63;
  const float* gp = g + pred * 512;
  const float* bp = bb + pred * 512;
  const float* wp = lw + pred * 512;
  bf16x8 v = *(const bf16x8*)(Hh + (size_t)rr * 512 + lane * 8);
  float xv[8];
  float s = 0.f;
  #pragma unroll
  for (int j = 0; j < 8; ++j) { xv[j] = bf2f((ushort_t)v[j]); s += xv[j]; }
  #pragma unroll
  for (int mm = 32; mm >= 1; mm >>= 1) s += __shfl_xor(s, mm, 64);
  const float mean = s * (1.f / 512.f);
  float vs = 0.f;
  #pragma unroll
  for (int j = 0; j < 8; ++j) { float d = xv[j] - mean; vs += d * d; }
  #pragma unroll
  for (int mm = 32; mm >= 1; mm >>= 1) vs += __shfl_xor(vs, mm, 64);
  const float rstd = rsqrtf(vs * (1.f / 512.f) + 1e-5f);
  const float4 g0 = ((const float4*)(gp + lane * 8))[0];
  const float4 g1 = ((const float4*)(gp + lane * 8))[1];
  const float4 b0 = ((const float4*)(bp + lane * 8))[0];
  const float4 b1 = ((const float4*)(bp + lane * 8))[1];
  const float4 w0 = ((const float4*)(wp + lane * 8))[0];
  const float4 w1 = ((const float4*)(wp + lane * 8))[1];
  const float gg[8] = {g0.x, g0.y, g0.z, g0.w, g1.x, g1.y, g1.z, g1.w};
  const float bv[8] = {b0.x, b0.y, b0.z, b0.w, b1.x, b1.y, b1.z, b1.w};
  const float ww[8] = {w0.x, w0.y, w0.z, w0.w, w1.x, w1.y, w1.z, w1.w};
  float dot = 0.f;
  #pragma unroll
  for (int j = 0; j < 8; ++j) dot += ((xv[j] - mean) * rstd * gg[j] + bv[j]) * ww[j];
  #pragma unroll
  for (int mm = 32; mm >= 1; mm >>= 1) dot += __shfl_xor(dot, mm, 64);
  if (lane == 0) {
    float val = dot + lbp[pred];
    if (mask[m]) val = 0.f;
    outp[pred * NB_M + m] = val;
  }
}

// ---------------- length regulator
__global__ __launch_bounds__(128) void k_regulate(const float* __restrict__ x3f, const int* __restrict__ cum,
                                                  float* __restrict__ xout) {
  const int bid = blockIdx.x;
  const int b = bid >> 11, f = bid & 2047;
  const int* c = cum + b * NB_T;
  int ml = c[511]; ml = ml < MAXL ? ml : MAXL;
  const int tid = threadIdx.x;
  float4 val = make_float4(0.f, 0.f, 0.f, 0.f);
  if (f < ml) {
    int lo = 0, hi = 512;
    while (lo < hi) { int mid = (lo + hi) >> 1; if (c[mid] <= f) lo = mid + 1; else hi = mid; }
    if (lo > 511) lo = 511;
    val = ((const float4*)(x3f + ((size_t)(b * NB_T + lo)) * 512))[tid];
  }
  ((float4*)(xout + ((size_t)(b * MAXL + f)) * 512))[tid] = val;
}

extern "C" void kernel_launch(void* const* d_in, const int* in_sizes, int n_in,
                              void* d_out, int out_size, void* d_ws, size_t ws_size,
                              hipStream_t stream) {
  const float* x        = (const float*)d_in[0];
  const unsigned char* src_mask = (const unsigned char*)d_in[1];
  const int* duration   = (const int*)d_in[2];
  const float* pitch_t  = (const float*)d_in[3];
  const float* energy_t = (const float*)d_in[4];
  const float* conv1_w  = (const float*)d_in[5];
  const float* conv1_b  = (const float*)d_in[6];
  const float* ln1_g    = (const float*)d_in[7];
  const float* ln1_b    = (const float*)d_in[8];
  const float* conv2_w  = (const float*)d_in[9];
  const float* conv2_b  = (const float*)d_in[10];
  const float* ln2_g    = (const float*)d_in[11];
  const float* ln2_b    = (const float*)d_in[12];
  const float* lin_w    = (const float*)d_in[13];
  const float* lin_b    = (const float*)d_in[14];
  const float* pbins    = (const float*)d_in[15];
  const float* ebins    = (const float*)d_in[16];
  const float* ptab     = (const float*)d_in[17];
  const float* etab     = (const float*)d_in[18];

  char* ws = (char*)d_ws;
  ushort_t* wt1    = (ushort_t*)(ws + 0);             //  4,718,592
  ushort_t* wt2    = (ushort_t*)(ws + 4718592);       //  4,718,592
  ushort_t* xb_pad = (ushort_t*)(ws + 9437184);       // 16,842,752  (aliased: lnp0)
  ushort_t* x2pad  = (ushort_t*)(ws + 26279936);      // 16,842,752  (aliased: lnp1)
  ushort_t* lnp2   = (ushort_t*)(ws + 43122688);      // 16,842,752
  ushort_t* hbuf   = (ushort_t*)(ws + 59965440);      // 50,331,648  (3 preds)
  float*    x3f    = (float*)   (ws + 110297088);     // 33,554,432
  int*      p_idx  = (int*)     (ws + 143851520);
  int*      e_idx  = (int*)     (ws + 143917056);
  int*      cum    = (int*)     (ws + 143982592);

  float* out      = (float*)d_out;
  float* o_xout   = out;                       // 33,554,432
  float* o_preds  = out + 33554432;            // 3 x 16384 (logd, pitch, energy)
  float* o_mellen = o_preds + 3 * NB_M;        // 32
  float* o_mmask  = o_mellen + 32;             // 65,536

  k_bucket<<<NB_M / 256, 256, 0, stream>>>(pitch_t, energy_t, pbins, ebins, p_idx, e_idx);
  k_cum<<<NB_B, 512, 0, stream>>>(duration, src_mask, cum, o_mellen, o_mmask);
  k_wt<<<dim3(64, 9), 256, 0, stream>>>(conv1_w, wt1);
  k_wt<<<dim3(64, 9), 256, 0, stream>>>(conv2_w, wt2);
  k_prep<<<NB_B * 514, 256, 0, stream>>>(x, ptab, etab, p_idx, e_idx, xb_pad, x2pad, lnp2, x3f);

  // conv1 for all 3 predictors (pred0,1 read xb_pad; pred2 reads x2pad)
  k_gemm<<<1536, 256, 0, stream>>>(xb_pad, xb_pad, x2pad, wt1, conv1_b, hbuf);
  // LN1 for all 3 (writes padded inputs for conv2; lnp0/lnp1 alias xb_pad/x2pad)
  k_ln_mid<<<3 * NB_M / 4, 256, 0, stream>>>(hbuf, ln1_g, ln1_b, xb_pad, x2pad, lnp2);
  // conv2 for all 3
  k_gemm<<<1536, 256, 0, stream>>>(xb_pad, x2pad, lnp2, wt2, conv2_b, hbuf);
  // LN2 + linear + mask -> all 3 predictions
  k_ln_fin<<<3 * NB_M / 4, 256, 0, stream>>>(hbuf, ln2_g, ln2_b, lin_w, lin_b, src_mask, o_preds);

  k_regulate<<<NB_B * MAXL, 128, 0, stream>>>(x3f, cum, o_xout);
}

// Round 6
// 496.043 us; speedup vs baseline: 1.1552x; 1.0145x over previous
//
#include <hip/hip_runtime.h>
#include <hip/hip_bf16.h>

typedef unsigned short ushort_t;
typedef unsigned int uint_t;
typedef __attribute__((ext_vector_type(8))) short bf16x8;
typedef __attribute__((ext_vector_type(4))) float f32x4;

#define NB_T 512
#define NB_B 32
#define NB_M (NB_B * NB_T)     // 16384
#define KDIM 1536
#define MAXL 2048
#define EPI_STRIDE 144         // shorts; 288 B rows for conflict-shifted epilogue bounce

__device__ __forceinline__ ushort_t f2bf(float f) {
  __hip_bfloat16 h = __float2bfloat16(f);
  return *reinterpret_cast<ushort_t*>(&h);
}
__device__ __forceinline__ float bf2f(ushort_t u) {
  __hip_bfloat16 h;
  *reinterpret_cast<ushort_t*>(&h) = u;
  return __bfloat162float(h);
}
__device__ __forceinline__ uint_t pack2(float a, float b) {
  return (uint_t)f2bf(a) | ((uint_t)f2bf(b) << 16);
}
__device__ __forceinline__ void gload_lds16(const void* g, void* l) {
  __builtin_amdgcn_global_load_lds((const __attribute__((address_space(1))) void*)g,
                                   (__attribute__((address_space(3))) void*)l, 16, 0, 0);
}

// ---------------- weight transpose (both convs in one dispatch):
// w[pk][i][o] f32 -> wt[p][o][kk*512+i] bf16
__global__ __launch_bounds__(256) void k_wt(const float* __restrict__ w1, const float* __restrict__ w2,
                                            ushort_t* __restrict__ wt1, ushort_t* __restrict__ wt2) {
  __shared__ float tile[64][65];
  int g = blockIdx.y;                 // 0..17
  const float* wsrc;
  ushort_t* wdst;
  if (g < 9) { wsrc = w1; wdst = wt1; } else { wsrc = w2; wdst = wt2; g -= 9; }
  const int p = g / 3, kk = g % 3;
  const int ot = (blockIdx.x & 7) * 64;
  const int it = (blockIdx.x >> 3) * 64;
  const int tx = threadIdx.x & 63;
  const int ty = threadIdx.x >> 6;
  const float* src = wsrc + (size_t)g * 512 * 512;
  #pragma unroll
  for (int r = ty; r < 64; r += 4)
    tile[r][tx] = src[(size_t)(it + r) * 512 + ot + tx];
  __syncthreads();
  #pragma unroll
  for (int r = ty; r < 64; r += 4)
    wdst[((size_t)(p * 512 + ot + r)) * KDIM + kk * 512 + it + tx] = f2bf(tile[tx][r]);
}

// ---------------- per-batch cumsum of masked duration + mel_len
__global__ __launch_bounds__(512) void k_cum(const int* __restrict__ dur, const unsigned char* __restrict__ mask,
                                             int* __restrict__ cum, float* __restrict__ mel_len_out) {
  __shared__ int s[512];
  const int b = blockIdx.x, t = threadIdx.x;
  int d = mask[b * NB_T + t] ? 0 : dur[b * NB_T + t];
  s[t] = d;
  __syncthreads();
  for (int off = 1; off < 512; off <<= 1) {
    int v = (t >= off) ? s[t - off] : 0;
    __syncthreads();
    s[t] += v;
    __syncthreads();
  }
  cum[b * NB_T + t] = s[t];
  if (t == 0) {
    int ml = s[511]; ml = ml < MAXL ? ml : MAXL;
    mel_len_out[b] = (float)ml;
  }
}

// ---------------- fused prep (+bucketize): xb_pad = bf(x), x2pad = bf(x + ptab[pi]),
//                  x3b = bf(x + ptab + etab), zero pad rows (xb/x2/lnp2)
__global__ __launch_bounds__(256) void k_prep(const float* __restrict__ x,
                                              const float* __restrict__ pt, const float* __restrict__ et,
                                              const float* __restrict__ pb, const float* __restrict__ eb,
                                              const float* __restrict__ ptab, const float* __restrict__ etab,
                                              ushort_t* __restrict__ xb_pad, ushort_t* __restrict__ x2pad,
                                              ushort_t* __restrict__ lnp2, ushort_t* __restrict__ x3b) {
  const int rp = blockIdx.x;               // 0..B*514-1
  const int b = rp / 514, j = rp % 514;
  const int tid = threadIdx.x;             // 2 elements each
  if (j == 0 || j == 513) {
    ((uint_t*)(xb_pad + (size_t)rp * 512))[tid] = 0u;
    ((uint_t*)(x2pad + (size_t)rp * 512))[tid] = 0u;
    ((uint_t*)(lnp2 + (size_t)rp * 512))[tid] = 0u;
    return;
  }
  const int m = b * NB_T + j - 1;
  // bucketize (redundant across threads; same-address broadcast loads)
  float v = pt[m];
  int lo = 0, hi = 255;
  while (lo < hi) { int mid = (lo + hi) >> 1; if (pb[mid] < v) lo = mid + 1; else hi = mid; }
  const int pi = lo;
  v = et[m]; lo = 0; hi = 255;
  while (lo < hi) { int mid = (lo + hi) >> 1; if (eb[mid] < v) lo = mid + 1; else hi = mid; }
  const int ei = lo;

  const float2 xv = ((const float2*)(x + (size_t)m * 512))[tid];
  const float2 pv = ((const float2*)(ptab + (size_t)pi * 512))[tid];
  const float2 ev = ((const float2*)(etab + (size_t)ei * 512))[tid];
  ((uint_t*)(xb_pad + (size_t)rp * 512))[tid] = pack2(xv.x, xv.y);
  const float ax = xv.x + pv.x, ay = xv.y + pv.y;
  ((uint_t*)(x2pad + (size_t)rp * 512))[tid] = pack2(ax, ay);
  ((uint_t*)(x3b + (size_t)m * 512))[tid] = pack2(ax + ev.x, ay + ev.y);
}

// ---------------- batched conv-as-GEMM, 3 predictors, 128x128 tile, dbuf LDS, 1 barrier/K-step
__global__ __launch_bounds__(256) void k_gemm(const ushort_t* __restrict__ A0,
                                              const ushort_t* __restrict__ A1,
                                              const ushort_t* __restrict__ A2,
                                              const ushort_t* __restrict__ Wt,
                                              const float* __restrict__ bias,
                                              ushort_t* __restrict__ H) {
  __shared__ short smem[18432];   // loop: 2 bufs x (A 4096 + B 4096) = 32KB; epi: 128x144 = 36KB
  const int tid = threadIdx.x;
  const int lane = tid & 63, wid = tid >> 6;

  // bijective XCD-chunked swizzle: 1536 blocks, q = 192 per XCD
  const int h = blockIdx.x;
  const int logical = (h & 7) * 192 + (h >> 3);
  const int pred = logical >> 9;
  const int tile = logical & 511;
  const int mt = tile >> 2, nt = tile & 3;
  const int m0 = mt * 128, n0 = nt * 128;
  const int b = m0 >> 9, t0 = m0 & 511;
  const long Arow0 = (long)b * 514 + t0 + 1;

  const ushort_t* Ap = (pred == 0) ? A0 : ((pred == 1) ? A1 : A2);
  const ushort_t* Wp = Wt + (size_t)pred * 512 * KDIM;
  const float* bp = bias + pred * 512;
  ushort_t* Hp = H + (size_t)pred * NB_M * 512;

  const int subr = lane >> 2;
  const int ioff = (lane & 3) * 8;
  const int wr = wid >> 1, wc = wid & 1;
  const int lr = lane & 15, kg = lane >> 4;

  f32x4 acc[4][4];
  #pragma unroll
  for (int i = 0; i < 4; ++i)
    #pragma unroll
    for (int j = 0; j < 4; ++j) acc[i][j] = (f32x4)0.f;

  auto STAGE = [&](int kk, int buf) {
    const int dt = (kk >> 4) - 1;
    const int i0 = (kk & 15) << 5;
    short* la = &smem[buf * 8192];
    short* lb = &smem[buf * 8192 + 4096];
    #pragma unroll
    for (int q = 0; q < 2; ++q) {
      const int chunk = wid * 2 + q;
      const int r = chunk * 16 + subr;
      gload_lds16(Ap + (size_t)(Arow0 + r + dt) * 512 + i0 + ioff, &la[chunk * 512]);
      gload_lds16(Wp + (size_t)(n0 + r) * KDIM + kk * 32 + ioff, &lb[chunk * 512]);
    }
  };

  STAGE(0, 0);
  __syncthreads();
  int buf = 0;
  for (int kk = 0; kk < 48; ++kk) {
    if (kk < 47) STAGE(kk + 1, buf ^ 1);
    const short* la = &smem[buf * 8192];
    const short* lb = &smem[buf * 8192 + 4096];
    bf16x8 af[4], bfv[4];
    #pragma unroll
    for (int fi = 0; fi < 4; ++fi)
      af[fi] = *(const bf16x8*)&la[(wr * 64 + fi * 16 + lr) * 32 + kg * 8];
    #pragma unroll
    for (int fj = 0; fj < 4; ++fj)
      bfv[fj] = *(const bf16x8*)&lb[(wc * 64 + fj * 16 + lr) * 32 + kg * 8];
    #pragma unroll
    for (int fi = 0; fi < 4; ++fi)
      #pragma unroll
      for (int fj = 0; fj < 4; ++fj)
        acc[fi][fj] = __builtin_amdgcn_mfma_f32_16x16x32_bf16(af[fi], bfv[fj], acc[fi][fj], 0, 0, 0);
    __syncthreads();   // drains vmcnt (next-tile stage) + covers LDS reuse
    buf ^= 1;
  }

  // epilogue: bias + relu -> bf16 via LDS bounce, then coalesced 16B stores
  float bvv[4];
  #pragma unroll
  for (int fj = 0; fj < 4; ++fj) bvv[fj] = bp[n0 + wc * 64 + fj * 16 + lr];
  #pragma unroll
  for (int fi = 0; fi < 4; ++fi) {
    const int rowb = wr * 64 + fi * 16 + kg * 4;
    #pragma unroll
    for (int fj = 0; fj < 4; ++fj) {
      const int col = wc * 64 + fj * 16 + lr;
      #pragma unroll
      for (int r = 0; r < 4; ++r) {
        float v = acc[fi][fj][r] + bvv[fj];
        v = v > 0.f ? v : 0.f;
        smem[(rowb + r) * EPI_STRIDE + col] = (short)f2bf(v);
      }
    }
  }
  __syncthreads();
  #pragma unroll
  for (int s = 0; s < 8; ++s) {
    const int chunk = tid + s * 256;        // 0..2047
    const int row = chunk >> 4, c8 = (chunk & 15) * 8;
    bf16x8 vv = *(const bf16x8*)&smem[row * EPI_STRIDE + c8];
    *(bf16x8*)(Hp + (size_t)(m0 + row) * 512 + n0 + c8) = vv;
  }
}

// ---------------- batched LayerNorm (wave per row) -> padded bf16 buffers
__global__ __launch_bounds__(256) void k_ln_mid(const ushort_t* __restrict__ Hh,
                                                const float* __restrict__ g, const float* __restrict__ bb,
                                                ushort_t* __restrict__ lnp0, ushort_t* __restrict__ lnp1,
                                                ushort_t* __restrict__ lnp2) {
  const int rr = blockIdx.x * 4 + (threadIdx.x >> 6);   // 0..3*NB_M-1
  const int pred = rr >> 14, m = rr & (NB_M - 1);
  const int lane = threadIdx.x & 63;
  const float* gp = g + pred * 512;
  const float* bp = bb + pred * 512;
  ushort_t* dst = (pred == 0) ? lnp0 : ((pred == 1) ? lnp1 : lnp2);
  bf16x8 v = *(const bf16x8*)(Hh + (size_t)rr * 512 + lane * 8);
  float xv[8];
  float s = 0.f;
  #pragma unroll
  for (int j = 0; j < 8; ++j) { xv[j] = bf2f((ushort_t)v[j]); s += xv[j]; }
  #pragma unroll
  for (int mm = 32; mm >= 1; mm >>= 1) s += __shfl_xor(s, mm, 64);
  const float mean = s * (1.f / 512.f);
  float vs = 0.f;
  #pragma unroll
  for (int j = 0; j < 8; ++j) { float d = xv[j] - mean; vs += d * d; }
  #pragma unroll
  for (int mm = 32; mm >= 1; mm >>= 1) vs += __shfl_xor(vs, mm, 64);
  const float rstd = rsqrtf(vs * (1.f / 512.f) + 1e-5f);
  const float4 g0 = ((const float4*)(gp + lane * 8))[0];
  const float4 g1 = ((const float4*)(gp + lane * 8))[1];
  const float4 b0 = ((const float4*)(bp + lane * 8))[0];
  const float4 b1 = ((const float4*)(bp + lane * 8))[1];
  const float gg[8] = {g0.x, g0.y, g0.z, g0.w, g1.x, g1.y, g1.z, g1.w};
  const float bv[8] = {b0.x, b0.y, b0.z, b0.w, b1.x, b1.y, b1.z, b1.w};
  bf16x8 o;
  #pragma unroll
  for (int j = 0; j < 8; ++j) o[j] = (short)f2bf((xv[j] - mean) * rstd * gg[j] + bv[j]);
  const int bidx = m >> 9, t = m & 511;
  *(bf16x8*)(dst + ((size_t)(bidx * 514 + t + 1)) * 512 + lane * 8) = o;
}

// ---------------- batched LayerNorm + linear proj + mask -> 3 pred outputs (contiguous)
__global__ __launch_bounds__(256) void k_ln_fin(const ushort_t* __restrict__ Hh,
                                                const float* __restrict__ g, const float* __restrict__ bb,
                                                const float* __restrict__ lw, const float* __restrict__ lbp,
                                                const unsigned char* __restrict__ mask,
                                                float* __restrict__ outp) {
  const int rr = blockIdx.x * 4 + (threadIdx.x >> 6);
  const int pred = rr >> 14, m = rr & (NB_M - 1);
  const int lane = threadIdx.x & 63;
  const float* gp = g + pred * 512;
  const float* bp = bb + pred * 512;
  const float* wp = lw + pred * 512;
  bf16x8 v = *(const bf16x8*)(Hh + (size_t)rr * 512 + lane * 8);
  float xv[8];
  float s = 0.f;
  #pragma unroll
  for (int j = 0; j < 8; ++j) { xv[j] = bf2f((ushort_t)v[j]); s += xv[j]; }
  #pragma unroll
  for (int mm = 32; mm >= 1; mm >>= 1) s += __shfl_xor(s, mm, 64);
  const float mean = s * (1.f / 512.f);
  float vs = 0.f;
  #pragma unroll
  for (int j = 0; j < 8; ++j) { float d = xv[j] - mean; vs += d * d; }
  #pragma unroll
  for (int mm = 32; mm >= 1; mm >>= 1) vs += __shfl_xor(vs, mm, 64);
  const float rstd = rsqrtf(vs * (1.f / 512.f) + 1e-5f);
  const float4 g0 = ((const float4*)(gp + lane * 8))[0];
  const float4 g1 = ((const float4*)(gp + lane * 8))[1];
  const float4 b0 = ((const float4*)(bp + lane * 8))[0];
  const float4 b1 = ((const float4*)(bp + lane * 8))[1];
  const float4 w0 = ((const float4*)(wp + lane * 8))[0];
  const float4 w1 = ((const float4*)(wp + lane * 8))[1];
  const float gg[8] = {g0.x, g0.y, g0.z, g0.w, g1.x, g1.y, g1.z, g1.w};
  const float bv[8] = {b0.x, b0.y, b0.z, b0.w, b1.x, b1.y, b1.z, b1.w};
  const float ww[8] = {w0.x, w0.y, w0.z, w0.w, w1.x, w1.y, w1.z, w1.w};
  float dot = 0.f;
  #pragma unroll
  for (int j = 0; j < 8; ++j) dot += ((xv[j] - mean) * rstd * gg[j] + bv[j]) * ww[j];
  #pragma unroll
  for (int mm = 32; mm >= 1; mm >>= 1) dot += __shfl_xor(dot, mm, 64);
  if (lane == 0) {
    float val = dot + lbp[pred];
    if (mask[m]) val = 0.f;
    outp[pred * NB_M + m] = val;
  }
}

// ---------------- length regulator: 1024 blocks (b x 64-frame chunk), cum in LDS,
//                  wave-per-frame copy, fused mel_mask write
__global__ __launch_bounds__(256) void k_regulate(const ushort_t* __restrict__ x3b, const int* __restrict__ cum,
                                                  float* __restrict__ xout, float* __restrict__ mmask) {
  __shared__ int c[512];
  const int blk = blockIdx.x;            // 0..1023
  const int b = blk >> 5, chunk = blk & 31;
  const int tid = threadIdx.x, lane = tid & 63, w = tid >> 6;
  c[tid] = cum[b * NB_T + tid];
  c[tid + 256] = cum[b * NB_T + tid + 256];
  __syncthreads();
  int ml = c[511]; ml = ml < MAXL ? ml : MAXL;
  const int f0 = chunk * 64 + w * 16;
  for (int i = 0; i < 16; ++i) {
    const int f = f0 + i;
    float o[8] = {0.f, 0.f, 0.f, 0.f, 0.f, 0.f, 0.f, 0.f};
    if (f < ml) {
      int lo = 0, hi = 512;
      while (lo < hi) { int mid = (lo + hi) >> 1; if (c[mid] <= f) lo = mid + 1; else hi = mid; }
      if (lo > 511) lo = 511;
      bf16x8 vv = *(const bf16x8*)(x3b + ((size_t)(b * NB_T + lo)) * 512 + lane * 8);
      #pragma unroll
      for (int j = 0; j < 8; ++j) o[j] = bf2f((ushort_t)vv[j]);
    }
    float* dst = xout + ((size_t)(b * MAXL + f)) * 512 + lane * 8;
    ((float4*)dst)[0] = make_float4(o[0], o[1], o[2], o[3]);
    ((float4*)dst)[1] = make_float4(o[4], o[5], o[6], o[7]);
    if (lane == 0) mmask[b * MAXL + f] = (f >= ml) ? 1.0f : 0.0f;
  }
}

extern "C" void kernel_launch(void* const* d_in, const int* in_sizes, int n_in,
                              void* d_out, int out_size, void* d_ws, size_t ws_size,
                              hipStream_t stream) {
  const float* x        = (const float*)d_in[0];
  const unsigned char* src_mask = (const unsigned char*)d_in[1];
  const int* duration   = (const int*)d_in[2];
  const float* pitch_t  = (const float*)d_in[3];
  const float* energy_t = (const float*)d_in[4];
  const float* conv1_w  = (const float*)d_in[5];
  const float* conv1_b  = (const float*)d_in[6];
  const float* ln1_g    = (const float*)d_in[7];
  const float* ln1_b    = (const float*)d_in[8];
  const float* conv2_w  = (const float*)d_in[9];
  const float* conv2_b  = (const float*)d_in[10];
  const float* ln2_g    = (const float*)d_in[11];
  const float* ln2_b    = (const float*)d_in[12];
  const float* lin_w    = (const float*)d_in[13];
  const float* lin_b    = (const float*)d_in[14];
  const float* pbins    = (const float*)d_in[15];
  const float* ebins    = (const float*)d_in[16];
  const float* ptab     = (const float*)d_in[17];
  const float* etab     = (const float*)d_in[18];

  char* ws = (char*)d_ws;
  ushort_t* wt1    = (ushort_t*)(ws + 0);             //  4,718,592
  ushort_t* wt2    = (ushort_t*)(ws + 4718592);       //  4,718,592
  ushort_t* xb_pad = (ushort_t*)(ws + 9437184);       // 16,842,752  (aliased: lnp0)
  ushort_t* x2pad  = (ushort_t*)(ws + 26279936);      // 16,842,752  (aliased: lnp1)
  ushort_t* lnp2   = (ushort_t*)(ws + 43122688);      // 16,842,752
  ushort_t* hbuf   = (ushort_t*)(ws + 59965440);      // 50,331,648  (3 preds)
  ushort_t* x3b    = (ushort_t*)(ws + 110297088);     // 16,777,216
  int*      cum    = (int*)     (ws + 127074304);     //     65,536

  float* out      = (float*)d_out;
  float* o_xout   = out;                       // 33,554,432
  float* o_preds  = out + 33554432;            // 3 x 16384 (logd, pitch, energy)
  float* o_mellen = o_preds + 3 * NB_M;        // 32
  float* o_mmask  = o_mellen + 32;             // 65,536

  k_cum<<<NB_B, 512, 0, stream>>>(duration, src_mask, cum, o_mellen);
  k_wt<<<dim3(64, 18), 256, 0, stream>>>(conv1_w, conv2_w, wt1, wt2);
  k_prep<<<NB_B * 514, 256, 0, stream>>>(x, pitch_t, energy_t, pbins, ebins, ptab, etab,
                                         xb_pad, x2pad, lnp2, x3b);

  // conv1 for all 3 predictors (pred0,1 read xb_pad; pred2 reads x2pad)
  k_gemm<<<1536, 256, 0, stream>>>(xb_pad, xb_pad, x2pad, wt1, conv1_b, hbuf);
  // LN1 for all 3 (writes padded inputs for conv2; lnp0/lnp1 alias xb_pad/x2pad)
  k_ln_mid<<<3 * NB_M / 4, 256, 0, stream>>>(hbuf, ln1_g, ln1_b, xb_pad, x2pad, lnp2);
  // conv2 for all 3
  k_gemm<<<1536, 256, 0, stream>>>(xb_pad, x2pad, lnp2, wt2, conv2_b, hbuf);
  // LN2 + linear + mask -> all 3 predictions
  k_ln_fin<<<3 * NB_M / 4, 256, 0, stream>>>(hbuf, ln2_g, ln2_b, lin_w, lin_b, src_mask, o_preds);

  k_regulate<<<1024, 256, 0, stream>>>(x3b, cum, o_xout, o_mmask);
}